// Round 5
// baseline (535.769 us; speedup 1.0000x reference)
//
#include <hip/hip_runtime.h>
#include <hip/hip_fp16.h>

// Problem: B=64, L=512, D=512, A=512
//   F_p = tanh(P @ W), F_h = tanh(H @ W)        [f16; 2-term split MFMA Ah*(Bh+Bl)]
//   S = F_p @ F_h^T ; attn = softmax_rows(S)
//   betas  = attn   @ H  -> d_out[0 .. 16M)
//   alphas = attn^T @ P  -> d_out[16M .. 32M)
//
// R5: B-operand fragments load DIRECTLY global->regs (W / HT / PT are L1/L2
// resident) -- deletes B LDS staging in proj & out_gemm (LDS 48/32 -> 16 KB,
// ~3 blocks/CU residency to hide the barrier drain). transpose_hp now reads
// the f16 X16 copy instead of re-reading f32 inputs (201 MB -> 134 MB).
//
// ws layout (f16 elems), total 100.66 MB (3*TOT):
//   [0, 2*TOT)    F_p|F_h  -- dead after score; reused for PT|HT
//   [2*TOT, 3*TOT) WT_H|WT_L (1MB, dead after proj) then attn
// d_out (128MB) doubles as scratch for X16 = f16(P|H) (67MB) until out_gemm.

#define NB 64
#define NL 512
#define ND 512
#define BATCH_ELEMS (512 * 512)            // 262144
#define TOT_ELEMS   ((size_t)NB * NL * ND) // 16777216

typedef _Float16 h8 __attribute__((ext_vector_type(8)));
typedef float f4 __attribute__((ext_vector_type(4)));

// LDS tile layout: [row][32 k] f16, 16B chunks XOR-swizzled by ((row>>1)^(row>>4))&3.
__device__ __forceinline__ int swz(int row, int chunk) {
    return (row << 5) + ((chunk ^ (((row >> 1) ^ (row >> 4)) & 3)) << 3);
}

// async global->LDS 16B: wave-uniform LDS base, per-lane global src.
__device__ __forceinline__ void gld16(const _Float16* g, _Float16* l) {
    __builtin_amdgcn_global_load_lds(
        (const __attribute__((address_space(1))) void*)g,
        (__attribute__((address_space(3))) void*)l, 16, 0, 0);
}

__device__ __forceinline__ float fast_tanh(float x) {
    float e = __expf(2.0f * x);            // inf-safe: x>>0 -> 1, x<<0 -> -1
    return 1.0f - 2.0f / (e + 1.0f);
}

// ------------- Prep: X16 = f16(P|H), stored in d_out scratch -----------------
__global__ __launch_bounds__(256) void conv16_kernel(
    const float* __restrict__ P, const float* __restrict__ H,
    _Float16* __restrict__ X16)
{
    const int z = blockIdx.z;
    const float* src = z ? H : P;
    _Float16* dst = X16 + (size_t)z * TOT_ELEMS;
    size_t i = ((size_t)blockIdx.x * 256 + threadIdx.x) * 8;
    float4 v0 = ((const float4*)(src + i))[0];
    float4 v1 = ((const float4*)(src + i))[1];
    h8 o;
    o[0] = (_Float16)v0.x; o[1] = (_Float16)v0.y;
    o[2] = (_Float16)v0.z; o[3] = (_Float16)v0.w;
    o[4] = (_Float16)v1.x; o[5] = (_Float16)v1.y;
    o[6] = (_Float16)v1.z; o[7] = (_Float16)v1.w;
    *(h8*)(dst + i) = o;
}

// ------------- Prep: W -> WT hi/lo f16 (1 block-layer, f32 source) -----------
template <bool WITH_LO>
__global__ __launch_bounds__(256) void transpose_f16_kernel(
    const float* __restrict__ src, _Float16* __restrict__ dstH,
    _Float16* __restrict__ dstL)
{
    __shared__ float tile[64 * 68];
    const size_t base = (size_t)blockIdx.z * BATCH_ELEMS;
    const int r0 = blockIdx.y * 64, c0 = blockIdx.x * 64;
    const int t = threadIdx.x;
    {
        int r = t >> 2, cq = (t & 3) * 16;
        const float* sp = src + base + (size_t)(r0 + r) * 512 + c0 + cq;
        *(float4*)&tile[r * 68 + cq]      = ((const float4*)sp)[0];
        *(float4*)&tile[r * 68 + cq + 4]  = ((const float4*)sp)[1];
        *(float4*)&tile[r * 68 + cq + 8]  = ((const float4*)sp)[2];
        *(float4*)&tile[r * 68 + cq + 12] = ((const float4*)sp)[3];
    }
    __syncthreads();
    {
        int c = t >> 2, rq = (t & 3) * 16;
        _Float16 hv[16], lv[16];
#pragma unroll
        for (int j = 0; j < 16; ++j) {
            float v = tile[(rq + j) * 68 + c];
            hv[j] = (_Float16)v;
            if (WITH_LO) lv[j] = (_Float16)(v - (float)hv[j]);
        }
        _Float16* dp = dstH + base + (size_t)(c0 + c) * 512 + r0 + rq;
        *(h8*)dp = *(h8*)&hv[0];
        *(h8*)(dp + 8) = *(h8*)&hv[8];
        if (WITH_LO) {
            _Float16* dl = dstL + base + (size_t)(c0 + c) * 512 + r0 + rq;
            *(h8*)dl = *(h8*)&lv[0];
            *(h8*)(dl + 8) = *(h8*)&lv[8];
        }
    }
}

// ------------- Prep: PT|HT from X16 (f16 -> f16 transpose) -------------------
// z in [0,128): src = X16 + z*BATCH (P batches then H), dst = ws + z*BATCH
// (PT region then HT region -- both contiguous in the same order).
__global__ __launch_bounds__(256) void transpose_hp16_kernel(
    const _Float16* __restrict__ X16, _Float16* __restrict__ dstbase)
{
    __shared__ __align__(16) _Float16 tile[64 * 64];
    const size_t base = (size_t)blockIdx.z * BATCH_ELEMS;
    const int r0 = blockIdx.y * 64, c0 = blockIdx.x * 64;
    const int t = threadIdx.x;
    {
        int r = t >> 2, cq = (t & 3) * 16;
        const _Float16* sp = X16 + base + (size_t)(r0 + r) * 512 + c0 + cq;
        h8 v0 = ((const h8*)sp)[0];
        h8 v1 = ((const h8*)sp)[1];
        int f = ((r >> 1) ^ (r >> 4)) & 7;
        *(h8*)&tile[r * 64 + (((cq >> 3) ^ f) << 3)]       = v0;
        *(h8*)&tile[r * 64 + ((((cq >> 3) + 1) ^ f) << 3)] = v1;
    }
    __syncthreads();
    {
        int c = t >> 2, rq = (t & 3) * 16;
        _Float16 hv[16];
#pragma unroll
        for (int j = 0; j < 16; ++j) {
            int row = rq + j;
            int f = ((row >> 1) ^ (row >> 4)) & 7;
            hv[j] = tile[row * 64 + (((c >> 3) ^ f) << 3) + (c & 7)];
        }
        _Float16* dp = dstbase + base + (size_t)(c0 + c) * 512 + r0 + rq;
        *(h8*)dp = *(h8*)&hv[0];
        *(h8*)(dp + 8) = *(h8*)&hv[8];
    }
}

// ---------------- Kernel 1: F = tanh(X16 @ W), 2-term split f16 MFMA ---------
// A: gld16 -> LDS (double-buffered). B (W hi/lo): direct global->reg fragments
// (L1/L2-resident), double-buffered in regs across the fully-unrolled k-loop.
__global__ __launch_bounds__(256, 3) void proj_tanh_kernel(
    const _Float16* __restrict__ X16,
    const _Float16* __restrict__ WTH, const _Float16* __restrict__ WTL,
    _Float16* __restrict__ Fout)
{
    __shared__ __align__(16) _Float16 AsH[2][128 * 32];

    const int z = blockIdx.z;
    const _Float16* X = X16 + (size_t)z * TOT_ELEMS;
    _Float16* F = Fout + (size_t)z * TOT_ELEMS;
    const int r0 = blockIdx.x * 128;
    const int n0 = blockIdx.y * 128;

    const int t = threadIdx.x;
    const int lane = t & 63, w4 = t >> 6;
    const int q = lane >> 4, c = lane & 15;
    const int wm = w4 >> 1, wn = w4 & 1;

    f4 acc[4][4] = {};

    // A gld16 source addressing (inverse-swizzled global src, linear LDS dest)
    const int lr = w4 * 16 + (lane >> 2);
    const int sb = ((lr >> 1) ^ (lr >> 4)) & 3;
    const int ch = ((lane & 3) ^ sb) * 8;
    const _Float16* sA0 = X + (size_t)(r0 + lr) * 512 + ch;
    const _Float16* sA1 = sA0 + (size_t)64 * 512;
    const int d0 = (w4 * 16) * 32, d1 = (64 + w4 * 16) * 32;

    // B fragment direct-global bases: content identical to old LDS-path frags
    const _Float16* bhg = WTH + (size_t)(n0 + wn * 64 + c) * 512 + q * 8;
    const _Float16* blg = WTL + (size_t)(n0 + wn * 64 + c) * 512 + q * 8;

    auto STAGE_A = [&](int pp, int k0) {
        gld16(sA0 + k0, &AsH[pp][d0]);
        gld16(sA1 + k0, &AsH[pp][d1]);
    };

    h8 bHc[4], bLc[4];
#pragma unroll
    for (int ni = 0; ni < 4; ++ni) {
        bHc[ni] = *(const h8*)(bhg + (size_t)ni * 16 * 512);
        bLc[ni] = *(const h8*)(blg + (size_t)ni * 16 * 512);
    }
    STAGE_A(0, 0);
    __syncthreads();

#pragma unroll
    for (int ks = 0; ks < 16; ++ks) {
        const int pp = ks & 1;
        const bool more = (ks + 1) < 16;
        const int k0n = (ks + 1) << 5;
        if (more) STAGE_A(pp ^ 1, k0n);

        h8 bHn[4], bLn[4];
        if (more) {
#pragma unroll
            for (int ni = 0; ni < 4; ++ni) {
                bHn[ni] = *(const h8*)(bhg + (size_t)ni * 16 * 512 + k0n);
                bLn[ni] = *(const h8*)(blg + (size_t)ni * 16 * 512 + k0n);
            }
        }

        h8 aH[4];
#pragma unroll
        for (int mi = 0; mi < 4; ++mi)
            aH[mi] = *(const h8*)&AsH[pp][swz(wm * 64 + mi * 16 + c, q)];
#pragma unroll
        for (int mi = 0; mi < 4; ++mi)
#pragma unroll
            for (int ni = 0; ni < 4; ++ni) {
                acc[mi][ni] = __builtin_amdgcn_mfma_f32_16x16x32_f16(aH[mi], bHc[ni], acc[mi][ni], 0, 0, 0);
                acc[mi][ni] = __builtin_amdgcn_mfma_f32_16x16x32_f16(aH[mi], bLc[ni], acc[mi][ni], 0, 0, 0);
            }
        __syncthreads();
        if (more) {
#pragma unroll
            for (int ni = 0; ni < 4; ++ni) { bHc[ni] = bHn[ni]; bLc[ni] = bLn[ni]; }
        }
    }

#pragma unroll
    for (int mi = 0; mi < 4; ++mi)
#pragma unroll
        for (int ni = 0; ni < 4; ++ni) {
            int col = n0 + wn * 64 + ni * 16 + c;
            int rowb = r0 + wm * 64 + mi * 16 + q * 4;
#pragma unroll
            for (int r = 0; r < 4; ++r)
                F[(size_t)(rowb + r) * 512 + col] = (_Float16)fast_tanh(acc[mi][ni][r]);
        }
}

// ---------------- Kernel 2: S = F_p @ F_h^T, row softmax -> attn f16 ---------
__global__ __launch_bounds__(256) void score_softmax_kernel(
    const _Float16* __restrict__ Fbase, _Float16* __restrict__ attn)
{
    __shared__ __align__(16) _Float16 As[2][64 * 32];
    __shared__ __align__(16) _Float16 Bs[2][512 * 32];
    __shared__ float redM[4 * 64], redS[4 * 64];

    const _Float16* Fp = Fbase;
    const _Float16* Fh = Fbase + TOT_ELEMS;
    const int b = blockIdx.y;
    const int p0 = blockIdx.x * 64;
    const size_t fb = (size_t)b * BATCH_ELEMS;

    const int t = threadIdx.x, lane = t & 63, w = t >> 6;
    const int q = lane >> 4, c = lane & 15;

    f4 acc[4][8] = {};

    const int lr = w * 16 + (lane >> 2);
    const int sb = ((lr >> 1) ^ (lr >> 4)) & 3;
    const int ch = ((lane & 3) ^ sb) * 8;
    const _Float16* sA  = Fp + fb + (size_t)(p0 + lr) * 512 + ch;
    const _Float16* sB0 = Fh + fb + (size_t)lr * 512 + ch;
    const int dA = (w * 16) * 32;

    auto STAGE = [&](int pp, int k0) {
        gld16(sA + k0, &As[pp][dA]);
#pragma unroll
        for (int i = 0; i < 8; ++i)
            gld16(sB0 + (size_t)i * 64 * 512 + k0, &Bs[pp][(i * 64 + w * 16) * 32]);
    };

    STAGE(0, 0);
    __syncthreads();

    for (int ks = 0; ks < 16; ++ks) {
        const int pp = ks & 1;
        if (ks + 1 < 16) STAGE(pp ^ 1, (ks + 1) << 5);

        h8 a[4], bb[8];
#pragma unroll
        for (int mt = 0; mt < 4; ++mt) a[mt] = *(const h8*)&As[pp][swz(mt * 16 + c, q)];
#pragma unroll
        for (int nt = 0; nt < 8; ++nt) bb[nt] = *(const h8*)&Bs[pp][swz(w * 128 + nt * 16 + c, q)];
#pragma unroll
        for (int mt = 0; mt < 4; ++mt)
#pragma unroll
            for (int nt = 0; nt < 8; ++nt)
                acc[mt][nt] = __builtin_amdgcn_mfma_f32_16x16x32_f16(a[mt], bb[nt], acc[mt][nt], 0, 0, 0);
        __syncthreads();
    }

    // ---- softmax over the 512 cols; rows owned: mt*16 + q*4 + r ----
    float rmax[4][4];
#pragma unroll
    for (int mt = 0; mt < 4; ++mt)
#pragma unroll
        for (int r = 0; r < 4; ++r) {
            float m = acc[mt][0][r];
#pragma unroll
            for (int nt = 1; nt < 8; ++nt) m = fmaxf(m, acc[mt][nt][r]);
            rmax[mt][r] = m;
        }
#pragma unroll
    for (int s = 1; s < 16; s <<= 1)
#pragma unroll
        for (int mt = 0; mt < 4; ++mt)
#pragma unroll
            for (int r = 0; r < 4; ++r)
                rmax[mt][r] = fmaxf(rmax[mt][r], __shfl_xor(rmax[mt][r], s, 64));
    if (c == 0)
#pragma unroll
        for (int mt = 0; mt < 4; ++mt)
#pragma unroll
            for (int r = 0; r < 4; ++r)
                redM[w * 64 + mt * 16 + q * 4 + r] = rmax[mt][r];
    __syncthreads();

    float gmax[4][4];
#pragma unroll
    for (int mt = 0; mt < 4; ++mt)
#pragma unroll
        for (int r = 0; r < 4; ++r) {
            int row = mt * 16 + q * 4 + r;
            float m = redM[row];
#pragma unroll
            for (int w4i = 1; w4i < 4; ++w4i) m = fmaxf(m, redM[w4i * 64 + row]);
            gmax[mt][r] = m;
        }

    float rsum[4][4] = {};
#pragma unroll
    for (int mt = 0; mt < 4; ++mt)
#pragma unroll
        for (int nt = 0; nt < 8; ++nt)
#pragma unroll
            for (int r = 0; r < 4; ++r) {
                float e = __expf(acc[mt][nt][r] - gmax[mt][r]);
                acc[mt][nt][r] = e;
                rsum[mt][r] += e;
            }
#pragma unroll
    for (int s = 1; s < 16; s <<= 1)
#pragma unroll
        for (int mt = 0; mt < 4; ++mt)
#pragma unroll
            for (int r = 0; r < 4; ++r)
                rsum[mt][r] += __shfl_xor(rsum[mt][r], s, 64);
    if (c == 0)
#pragma unroll
        for (int mt = 0; mt < 4; ++mt)
#pragma unroll
            for (int r = 0; r < 4; ++r)
                redS[w * 64 + mt * 16 + q * 4 + r] = rsum[mt][r];
    __syncthreads();

    float inv[4][4];
#pragma unroll
    for (int mt = 0; mt < 4; ++mt)
#pragma unroll
        for (int r = 0; r < 4; ++r) {
            int row = mt * 16 + q * 4 + r;
            float s = redS[row] + redS[64 + row] + redS[128 + row] + redS[192 + row];
            inv[mt][r] = 1.0f / s;
        }

#pragma unroll
    for (int mt = 0; mt < 4; ++mt)
#pragma unroll
        for (int nt = 0; nt < 8; ++nt) {
            int col = w * 128 + nt * 16 + c;
#pragma unroll
            for (int r = 0; r < 4; ++r) {
                int row = p0 + mt * 16 + q * 4 + r;
                attn[fb + (size_t)row * 512 + col] = (_Float16)(acc[mt][nt][r] * inv[mt][r]);
            }
        }
}

// ------- Kernels 3+4 merged: C = A(^T) @ B; z<64: betas (attn@H via HT),
//         z>=64: alphas (attn^T@P via PT). A via LDS; B direct global->reg. --
__global__ __launch_bounds__(256, 3) void out_gemm_kernel(
    const _Float16* __restrict__ Amat, const _Float16* __restrict__ HT,
    const _Float16* __restrict__ PT, float* __restrict__ out)
{
    __shared__ __align__(16) _Float16 As[2][128 * 32];

    const int zz = blockIdx.z;
    const bool transA = zz >= NB;
    const int b = transA ? zz - NB : zz;
    const _Float16* BT = transA ? PT : HT;
    float* Cout = transA ? out + TOT_ELEMS : out;

    const int bn = blockIdx.x * 128, bm = blockIdx.y * 128;
    const size_t base = (size_t)b * BATCH_ELEMS;

    const int t = threadIdx.x, lane = t & 63, w4 = t >> 6;
    const int q = lane >> 4, c = lane & 15;
    const int wm = w4 >> 1, wn = w4 & 1;

    f4 acc[4][4] = {};

    // A gld16 addressing (direct path)
    const int lr = w4 * 16 + (lane >> 2);
    const int sb = ((lr >> 1) ^ (lr >> 4)) & 3;
    const int ch = ((lane & 3) ^ sb) * 8;
    const _Float16* sA0 = Amat + base + (size_t)(bm + lr) * 512 + ch;
    const _Float16* sA1 = sA0 + (size_t)64 * 512;
    const int d0 = (w4 * 16) * 32, d1 = (64 + w4 * 16) * 32;

    // transA reg-staged scatter addressing
    const int kk = t >> 3, m0 = (t & 7) * 16;
    const _Float16* apg_t = Amat + base + (size_t)kk * 512 + bm + m0;
    h8 a0, a1;

    // B fragment direct-global base
    const _Float16* bfg = BT + base + (size_t)(bn + wn * 64 + c) * 512 + q * 8;

    auto STAGE_A_DIRECT = [&](int pp, int k0) {
        gld16(sA0 + k0, &As[pp][d0]);
        gld16(sA1 + k0, &As[pp][d1]);
    };
    auto LOAD_A_T = [&](int k0) {
        a0 = ((const h8*)(apg_t + (size_t)k0 * 512))[0];
        a1 = ((const h8*)(apg_t + (size_t)k0 * 512))[1];
    };
    auto STAGE_A_T = [&](int pp) {
#pragma unroll
        for (int j = 0; j < 8; ++j) {
            As[pp][swz(m0 + j, kk >> 3) + (kk & 7)]     = a0[j];
            As[pp][swz(m0 + 8 + j, kk >> 3) + (kk & 7)] = a1[j];
        }
    };

    h8 bbc[4];
#pragma unroll
    for (int ni = 0; ni < 4; ++ni)
        bbc[ni] = *(const h8*)(bfg + (size_t)ni * 16 * 512);
    if (!transA) {
        STAGE_A_DIRECT(0, 0);
    } else {
        LOAD_A_T(0);
        STAGE_A_T(0);
    }
    __syncthreads();

#pragma unroll
    for (int ks = 0; ks < 16; ++ks) {
        const int pp = ks & 1;
        const bool more = (ks + 1) < 16;
        const int k0n = (ks + 1) << 5;
        if (more) {
            if (!transA) STAGE_A_DIRECT(pp ^ 1, k0n);
            else LOAD_A_T(k0n);
        }
        h8 bbn[4];
        if (more) {
#pragma unroll
            for (int ni = 0; ni < 4; ++ni)
                bbn[ni] = *(const h8*)(bfg + (size_t)ni * 16 * 512 + k0n);
        }

        h8 a[4];
#pragma unroll
        for (int mi = 0; mi < 4; ++mi) a[mi] = *(const h8*)&As[pp][swz(wm * 64 + mi * 16 + c, q)];
#pragma unroll
        for (int mi = 0; mi < 4; ++mi)
#pragma unroll
            for (int ni = 0; ni < 4; ++ni)
                acc[mi][ni] = __builtin_amdgcn_mfma_f32_16x16x32_f16(a[mi], bbc[ni], acc[mi][ni], 0, 0, 0);
        if (more && transA) STAGE_A_T(pp ^ 1);
        __syncthreads();
        if (more) {
#pragma unroll
            for (int ni = 0; ni < 4; ++ni) bbc[ni] = bbn[ni];
        }
    }

#pragma unroll
    for (int mi = 0; mi < 4; ++mi)
#pragma unroll
        for (int ni = 0; ni < 4; ++ni) {
            int col = bn + wn * 64 + ni * 16 + c;
            int rowb = bm + wm * 64 + mi * 16 + q * 4;
#pragma unroll
            for (int r = 0; r < 4; ++r)
                Cout[base + (size_t)(rowb + r) * 512 + col] = acc[mi][ni][r];
        }
}

extern "C" void kernel_launch(void* const* d_in, const int* in_sizes, int n_in,
                              void* d_out, int out_size, void* d_ws, size_t ws_size,
                              hipStream_t stream) {
    const float* P = (const float*)d_in[0];
    const float* H = (const float*)d_in[1];
    const float* W = (const float*)d_in[2];
    float* out = (float*)d_out;

    _Float16* ws16 = (_Float16*)d_ws;
    _Float16* F    = ws16;                       // F_p|F_h: 2*TOT (dead after score)
    _Float16* PT   = ws16;                       // reuses F region after score
    _Float16* HT   = ws16 + TOT_ELEMS;
    _Float16* attn = ws16 + 2 * TOT_ELEMS;       // TOT
    _Float16* WTH  = attn;                       // WT lives in attn region (dead
    _Float16* WTL  = attn + BATCH_ELEMS;         //  before score writes attn)
    _Float16* X16  = (_Float16*)d_out;           // d_out scratch: dead before out_gemm

    conv16_kernel<<<dim3(8192, 1, 2), 256, 0, stream>>>(P, H, X16);
    transpose_f16_kernel<true><<<dim3(8, 8, 1), 256, 0, stream>>>(W, WTH, WTL);
    proj_tanh_kernel<<<dim3(256, 4, 2), 256, 0, stream>>>(X16, WTH, WTL, F);
    score_softmax_kernel<<<dim3(8, NB), 256, 0, stream>>>(F, attn);
    // PT region = ws[0..TOT) from X16 P-half; HT = ws[TOT..2TOT) from H-half:
    // single launch, z spans both (src and dst offsets are the same linear map).
    transpose_hp16_kernel<<<dim3(8, 8, 2 * NB), 256, 0, stream>>>(X16, ws16);
    out_gemm_kernel<<<dim3(4, 4, 2 * NB), 256, 0, stream>>>(attn, HT, PT, out);
}

// Round 6
// 503.966 us; speedup vs baseline: 1.0631x; 1.0631x over previous
//
#include <hip/hip_runtime.h>
#include <hip/hip_fp16.h>

// Problem: B=64, L=512, D=512, A=512
//   F_p = tanh(P @ W), F_h = tanh(H @ W)        [f16; 2-term split MFMA Ah*(Bh+Bl)]
//   S = F_p @ F_h^T ; attn = softmax_rows(S)
//   betas  = attn   @ H  -> d_out[0 .. 16M)     [FUSED into score kernel]
//   alphas = attn^T @ P  -> d_out[16M .. 32M)
//
// R6: betas fused into score (block owns attn rows; A = attn re-read via gld16
// L2-hit, B = HT direct->reg). PT eliminated (alphas stages B from f32 P with
// an in-kernel transpose-convert scatter). proj reverted to R4 form (109us).
//
// ws (f16, 3*TOT): F_p|F_h [0,2T) -- dead after score;  attn [2T,3T)
//                  (WTH|WTL live in attn region until proj done)
// d_out (f16-capacity 4*TOT): X16 [0,2T) -- dead after proj+transpose;
//                  HT [2T,3T) -- dead after score.
//   betas  f32 -> bytes [0,67MB)    = X16 region (dead)    [written by score]
//   alphas f32 -> bytes [67,134MB)  = HT region (dead)     [written by alphas]

#define NB 64
#define NL 512
#define ND 512
#define BATCH_ELEMS (512 * 512)            // 262144
#define TOT_ELEMS   ((size_t)NB * NL * ND) // 16777216

typedef _Float16 h8 __attribute__((ext_vector_type(8)));
typedef float f4 __attribute__((ext_vector_type(4)));

// LDS tile layout: [row][32 k] f16, 16B chunks XOR-swizzled by ((row>>1)^(row>>4))&3.
__device__ __forceinline__ int swz(int row, int chunk) {
    return (row << 5) + ((chunk ^ (((row >> 1) ^ (row >> 4)) & 3)) << 3);
}

// async global->LDS 16B: wave-uniform LDS base, per-lane global src.
__device__ __forceinline__ void gld16(const _Float16* g, _Float16* l) {
    __builtin_amdgcn_global_load_lds(
        (const __attribute__((address_space(1))) void*)g,
        (__attribute__((address_space(3))) void*)l, 16, 0, 0);
}

__device__ __forceinline__ float fast_tanh(float x) {
    float e = __expf(2.0f * x);            // inf-safe: x>>0 -> 1, x<<0 -> -1
    return 1.0f - 2.0f / (e + 1.0f);
}

// ------------- Prep: X16 = f16(P|H), stored in d_out scratch -----------------
__global__ __launch_bounds__(256) void conv16_kernel(
    const float* __restrict__ P, const float* __restrict__ H,
    _Float16* __restrict__ X16)
{
    const int z = blockIdx.z;
    const float* src = z ? H : P;
    _Float16* dst = X16 + (size_t)z * TOT_ELEMS;
    size_t i = ((size_t)blockIdx.x * 256 + threadIdx.x) * 8;
    float4 v0 = ((const float4*)(src + i))[0];
    float4 v1 = ((const float4*)(src + i))[1];
    h8 o;
    o[0] = (_Float16)v0.x; o[1] = (_Float16)v0.y;
    o[2] = (_Float16)v0.z; o[3] = (_Float16)v0.w;
    o[4] = (_Float16)v1.x; o[5] = (_Float16)v1.y;
    o[6] = (_Float16)v1.z; o[7] = (_Float16)v1.w;
    *(h8*)(dst + i) = o;
}

// ------------- Prep: W -> WT hi/lo f16 (1 block-layer, f32 source) -----------
template <bool WITH_LO>
__global__ __launch_bounds__(256) void transpose_f16_kernel(
    const float* __restrict__ src, _Float16* __restrict__ dstH,
    _Float16* __restrict__ dstL)
{
    __shared__ float tile[64 * 68];
    const size_t base = (size_t)blockIdx.z * BATCH_ELEMS;
    const int r0 = blockIdx.y * 64, c0 = blockIdx.x * 64;
    const int t = threadIdx.x;
    {
        int r = t >> 2, cq = (t & 3) * 16;
        const float* sp = src + base + (size_t)(r0 + r) * 512 + c0 + cq;
        *(float4*)&tile[r * 68 + cq]      = ((const float4*)sp)[0];
        *(float4*)&tile[r * 68 + cq + 4]  = ((const float4*)sp)[1];
        *(float4*)&tile[r * 68 + cq + 8]  = ((const float4*)sp)[2];
        *(float4*)&tile[r * 68 + cq + 12] = ((const float4*)sp)[3];
    }
    __syncthreads();
    {
        int c = t >> 2, rq = (t & 3) * 16;
        _Float16 hv[16], lv[16];
#pragma unroll
        for (int j = 0; j < 16; ++j) {
            float v = tile[(rq + j) * 68 + c];
            hv[j] = (_Float16)v;
            if (WITH_LO) lv[j] = (_Float16)(v - (float)hv[j]);
        }
        _Float16* dp = dstH + base + (size_t)(c0 + c) * 512 + r0 + rq;
        *(h8*)dp = *(h8*)&hv[0];
        *(h8*)(dp + 8) = *(h8*)&hv[8];
        if (WITH_LO) {
            _Float16* dl = dstL + base + (size_t)(c0 + c) * 512 + r0 + rq;
            *(h8*)dl = *(h8*)&lv[0];
            *(h8*)(dl + 8) = *(h8*)&lv[8];
        }
    }
}

// ------------- Prep: HT from X16 H-half (f16 -> f16 transpose) ---------------
__global__ __launch_bounds__(256) void transpose_h16_kernel(
    const _Float16* __restrict__ Xh, _Float16* __restrict__ HT)
{
    __shared__ __align__(16) _Float16 tile[64 * 64];
    const size_t base = (size_t)blockIdx.z * BATCH_ELEMS;
    const int r0 = blockIdx.y * 64, c0 = blockIdx.x * 64;
    const int t = threadIdx.x;
    {
        int r = t >> 2, cq = (t & 3) * 16;
        const _Float16* sp = Xh + base + (size_t)(r0 + r) * 512 + c0 + cq;
        h8 v0 = ((const h8*)sp)[0];
        h8 v1 = ((const h8*)sp)[1];
        int f = ((r >> 1) ^ (r >> 4)) & 7;
        *(h8*)&tile[r * 64 + (((cq >> 3) ^ f) << 3)]       = v0;
        *(h8*)&tile[r * 64 + ((((cq >> 3) + 1) ^ f) << 3)] = v1;
    }
    __syncthreads();
    {
        int c = t >> 2, rq = (t & 3) * 16;
        _Float16 hv[16];
#pragma unroll
        for (int j = 0; j < 16; ++j) {
            int row = rq + j;
            int f = ((row >> 1) ^ (row >> 4)) & 7;
            hv[j] = tile[row * 64 + (((c >> 3) ^ f) << 3) + (c & 7)];
        }
        _Float16* dp = HT + base + (size_t)(c0 + c) * 512 + r0 + rq;
        *(h8*)dp = *(h8*)&hv[0];
        *(h8*)(dp + 8) = *(h8*)&hv[8];
    }
}

// ---------------- Kernel 1: F = tanh(X16 @ W), 2-term split f16 MFMA ---------
// R4 form (measured 109us): all staging via gld16, 1 barrier/k-step.
__global__ __launch_bounds__(256) void proj_tanh_kernel(
    const _Float16* __restrict__ X16,
    const _Float16* __restrict__ WTH, const _Float16* __restrict__ WTL,
    _Float16* __restrict__ Fout)
{
    __shared__ __align__(16) _Float16 AsH[2][128 * 32];
    __shared__ __align__(16) _Float16 BsH[2][128 * 32], BsL[2][128 * 32];

    const int z = blockIdx.z;
    const _Float16* X = X16 + (size_t)z * TOT_ELEMS;
    _Float16* F = Fout + (size_t)z * TOT_ELEMS;
    const int r0 = blockIdx.x * 128;
    const int n0 = blockIdx.y * 128;

    const int t = threadIdx.x;
    const int lane = t & 63, w4 = t >> 6;
    const int q = lane >> 4, c = lane & 15;
    const int wm = w4 >> 1, wn = w4 & 1;

    f4 acc[4][4] = {};

    const int lr = w4 * 16 + (lane >> 2);
    const int sb = ((lr >> 1) ^ (lr >> 4)) & 3;
    const int ch = ((lane & 3) ^ sb) * 8;
    const _Float16* sA0 = X + (size_t)(r0 + lr) * 512 + ch;
    const _Float16* sA1 = sA0 + (size_t)64 * 512;
    const _Float16* sH0 = WTH + (size_t)(n0 + lr) * 512 + ch;
    const _Float16* sH1 = sH0 + (size_t)64 * 512;
    const _Float16* sL0 = WTL + (size_t)(n0 + lr) * 512 + ch;
    const _Float16* sL1 = sL0 + (size_t)64 * 512;
    const int d0 = (w4 * 16) * 32, d1 = (64 + w4 * 16) * 32;

    auto STAGE = [&](int pp, int k0) {
        gld16(sA0 + k0, &AsH[pp][d0]);
        gld16(sA1 + k0, &AsH[pp][d1]);
        gld16(sH0 + k0, &BsH[pp][d0]);
        gld16(sH1 + k0, &BsH[pp][d1]);
        gld16(sL0 + k0, &BsL[pp][d0]);
        gld16(sL1 + k0, &BsL[pp][d1]);
    };

    STAGE(0, 0);
    __syncthreads();

    for (int ks = 0; ks < 16; ++ks) {
        const int pp = ks & 1;
        if (ks + 1 < 16) STAGE(pp ^ 1, (ks + 1) << 5);

        h8 aH[4], bH[4], bL[4];
#pragma unroll
        for (int mi = 0; mi < 4; ++mi)
            aH[mi] = *(const h8*)&AsH[pp][swz(wm * 64 + mi * 16 + c, q)];
#pragma unroll
        for (int ni = 0; ni < 4; ++ni) {
            bH[ni] = *(const h8*)&BsH[pp][swz(wn * 64 + ni * 16 + c, q)];
            bL[ni] = *(const h8*)&BsL[pp][swz(wn * 64 + ni * 16 + c, q)];
        }
#pragma unroll
        for (int mi = 0; mi < 4; ++mi)
#pragma unroll
            for (int ni = 0; ni < 4; ++ni) {
                acc[mi][ni] = __builtin_amdgcn_mfma_f32_16x16x32_f16(aH[mi], bH[ni], acc[mi][ni], 0, 0, 0);
                acc[mi][ni] = __builtin_amdgcn_mfma_f32_16x16x32_f16(aH[mi], bL[ni], acc[mi][ni], 0, 0, 0);
            }
        __syncthreads();
    }

#pragma unroll
    for (int mi = 0; mi < 4; ++mi)
#pragma unroll
        for (int ni = 0; ni < 4; ++ni) {
            int col = n0 + wn * 64 + ni * 16 + c;
            int rowb = r0 + wm * 64 + mi * 16 + q * 4;
#pragma unroll
            for (int r = 0; r < 4; ++r)
                F[(size_t)(rowb + r) * 512 + col] = (_Float16)fast_tanh(acc[mi][ni][r]);
        }
}

// ------ Kernel 2: S = F_p @ F_h^T, row softmax -> attn f16, THEN betas -------
// betas = attn(64x512, this block's rows) @ H = attn @ HT^T -> out f32.
// A re-read via gld16 (attn is L2-hot: just written by this block);
// B = HT fragments direct global->reg (L2-resident, 512KB/batch).
__global__ __launch_bounds__(256) void score_softmax_beta_kernel(
    const _Float16* __restrict__ Fbase, const _Float16* __restrict__ HT,
    _Float16* __restrict__ attn, float* __restrict__ outB)
{
    __shared__ __align__(16) _Float16 As[2][64 * 32];
    __shared__ __align__(16) _Float16 Bs[2][512 * 32];
    __shared__ float redM[4 * 64], redS[4 * 64];

    const _Float16* Fp = Fbase;
    const _Float16* Fh = Fbase + TOT_ELEMS;
    const int b = blockIdx.y;
    const int p0 = blockIdx.x * 64;
    const size_t fb = (size_t)b * BATCH_ELEMS;

    const int t = threadIdx.x, lane = t & 63, w = t >> 6;
    const int q = lane >> 4, c = lane & 15;

    f4 acc[4][8] = {};

    const int lr = w * 16 + (lane >> 2);
    const int sb = ((lr >> 1) ^ (lr >> 4)) & 3;
    const int ch = ((lane & 3) ^ sb) * 8;
    const _Float16* sA  = Fp + fb + (size_t)(p0 + lr) * 512 + ch;
    const _Float16* sB0 = Fh + fb + (size_t)lr * 512 + ch;
    const int dA = (w * 16) * 32;

    auto STAGE = [&](int pp, int k0) {
        gld16(sA + k0, &As[pp][dA]);
#pragma unroll
        for (int i = 0; i < 8; ++i)
            gld16(sB0 + (size_t)i * 64 * 512 + k0, &Bs[pp][(i * 64 + w * 16) * 32]);
    };

    STAGE(0, 0);
    __syncthreads();

    for (int ks = 0; ks < 16; ++ks) {
        const int pp = ks & 1;
        if (ks + 1 < 16) STAGE(pp ^ 1, (ks + 1) << 5);

        h8 a[4], bb[8];
#pragma unroll
        for (int mt = 0; mt < 4; ++mt) a[mt] = *(const h8*)&As[pp][swz(mt * 16 + c, q)];
#pragma unroll
        for (int nt = 0; nt < 8; ++nt) bb[nt] = *(const h8*)&Bs[pp][swz(w * 128 + nt * 16 + c, q)];
#pragma unroll
        for (int mt = 0; mt < 4; ++mt)
#pragma unroll
            for (int nt = 0; nt < 8; ++nt)
                acc[mt][nt] = __builtin_amdgcn_mfma_f32_16x16x32_f16(a[mt], bb[nt], acc[mt][nt], 0, 0, 0);
        __syncthreads();
    }

    // ---- softmax over the 512 cols; rows owned: mt*16 + q*4 + r ----
    float rmax[4][4];
#pragma unroll
    for (int mt = 0; mt < 4; ++mt)
#pragma unroll
        for (int r = 0; r < 4; ++r) {
            float m = acc[mt][0][r];
#pragma unroll
            for (int nt = 1; nt < 8; ++nt) m = fmaxf(m, acc[mt][nt][r]);
            rmax[mt][r] = m;
        }
#pragma unroll
    for (int s = 1; s < 16; s <<= 1)
#pragma unroll
        for (int mt = 0; mt < 4; ++mt)
#pragma unroll
            for (int r = 0; r < 4; ++r)
                rmax[mt][r] = fmaxf(rmax[mt][r], __shfl_xor(rmax[mt][r], s, 64));
    if (c == 0)
#pragma unroll
        for (int mt = 0; mt < 4; ++mt)
#pragma unroll
            for (int r = 0; r < 4; ++r)
                redM[w * 64 + mt * 16 + q * 4 + r] = rmax[mt][r];
    __syncthreads();

    float gmax[4][4];
#pragma unroll
    for (int mt = 0; mt < 4; ++mt)
#pragma unroll
        for (int r = 0; r < 4; ++r) {
            int row = mt * 16 + q * 4 + r;
            float m = redM[row];
#pragma unroll
            for (int w4i = 1; w4i < 4; ++w4i) m = fmaxf(m, redM[w4i * 64 + row]);
            gmax[mt][r] = m;
        }

    float rsum[4][4] = {};
#pragma unroll
    for (int mt = 0; mt < 4; ++mt)
#pragma unroll
        for (int nt = 0; nt < 8; ++nt)
#pragma unroll
            for (int r = 0; r < 4; ++r) {
                float e = __expf(acc[mt][nt][r] - gmax[mt][r]);
                acc[mt][nt][r] = e;
                rsum[mt][r] += e;
            }
#pragma unroll
    for (int s = 1; s < 16; s <<= 1)
#pragma unroll
        for (int mt = 0; mt < 4; ++mt)
#pragma unroll
            for (int r = 0; r < 4; ++r)
                rsum[mt][r] += __shfl_xor(rsum[mt][r], s, 64);
    if (c == 0)
#pragma unroll
        for (int mt = 0; mt < 4; ++mt)
#pragma unroll
            for (int r = 0; r < 4; ++r)
                redS[w * 64 + mt * 16 + q * 4 + r] = rsum[mt][r];
    __syncthreads();

    float inv[4][4];
#pragma unroll
    for (int mt = 0; mt < 4; ++mt)
#pragma unroll
        for (int r = 0; r < 4; ++r) {
            int row = mt * 16 + q * 4 + r;
            float s = redS[row] + redS[64 + row] + redS[128 + row] + redS[192 + row];
            inv[mt][r] = 1.0f / s;
        }

#pragma unroll
    for (int mt = 0; mt < 4; ++mt)
#pragma unroll
        for (int nt = 0; nt < 8; ++nt) {
            int col = w * 128 + nt * 16 + c;
#pragma unroll
            for (int r = 0; r < 4; ++r) {
                int row = p0 + mt * 16 + q * 4 + r;
                attn[fb + (size_t)row * 512 + col] = (_Float16)(acc[mt][nt][r] * inv[mt][r]);
            }
        }
    // barrier: compiler emits vmcnt(0) drain -> attn stores visible in L2
    __syncthreads();

    // ---- betas: bacc = attn[p0..p0+64) @ H  (B-frags from HT rows d) --------
    f4 bacc[4][8] = {};
    const _Float16* sA2 = attn + fb + (size_t)(p0 + lr) * 512 + ch;
    const _Float16* bhg = HT + fb + (size_t)(w * 128 + c) * 512 + q * 8;

    gld16(sA2, &As[0][dA]);
    __syncthreads();

    for (int ks = 0; ks < 16; ++ks) {
        const int pp = ks & 1;
        const int k0 = ks << 5;
        if (ks + 1 < 16) gld16(sA2 + ((ks + 1) << 5), &As[pp ^ 1][dA]);

        h8 bb2[8];
#pragma unroll
        for (int nt = 0; nt < 8; ++nt)
            bb2[nt] = *(const h8*)(bhg + (size_t)nt * 16 * 512 + k0);
        h8 a2[4];
#pragma unroll
        for (int mt = 0; mt < 4; ++mt) a2[mt] = *(const h8*)&As[pp][swz(mt * 16 + c, q)];
#pragma unroll
        for (int mt = 0; mt < 4; ++mt)
#pragma unroll
            for (int nt = 0; nt < 8; ++nt)
                bacc[mt][nt] = __builtin_amdgcn_mfma_f32_16x16x32_f16(a2[mt], bb2[nt], bacc[mt][nt], 0, 0, 0);
        __syncthreads();
    }

#pragma unroll
    for (int mt = 0; mt < 4; ++mt)
#pragma unroll
        for (int nt = 0; nt < 8; ++nt) {
            int col = w * 128 + nt * 16 + c;
#pragma unroll
            for (int r = 0; r < 4; ++r) {
                int row = p0 + mt * 16 + q * 4 + r;
                outB[fb + (size_t)row * 512 + col] = bacc[mt][nt][r];
            }
        }
}

// ------- Kernel 3: alphas = attn^T @ P. A: attn transposed-scatter (f16);
//         B: P f32 transpose-convert scatter (no PT buffer needed). ---------
__global__ __launch_bounds__(256) void alphas_gemm_kernel(
    const _Float16* __restrict__ attn, const float* __restrict__ P,
    float* __restrict__ outA)
{
    __shared__ __align__(16) _Float16 As[2][128 * 32];
    __shared__ __align__(16) _Float16 Bs[2][128 * 32];

    const int b = blockIdx.z;
    const int bn = blockIdx.x * 128, bm = blockIdx.y * 128;   // bm: h-tile, bn: d-tile
    const size_t base = (size_t)b * BATCH_ELEMS;

    const int t = threadIdx.x, lane = t & 63, w4 = t >> 6;
    const int q = lane >> 4, c = lane & 15;
    const int wm = w4 >> 1, wn = w4 & 1;

    f4 acc[4][4] = {};

    // staging thread mapping: kk = p-row within k-tile, m0 = 16-wide col group
    const int kk = t >> 3, m0 = (t & 7) * 16;
    const _Float16* apg = attn + base + (size_t)kk * 512 + bm + m0;
    const float*    bpg = P    + base + (size_t)kk * 512 + bn + m0;

    h8 a0, a1;
    float bv[16];

    auto LOAD = [&](int k0) {
        a0 = ((const h8*)(apg + (size_t)k0 * 512))[0];
        a1 = ((const h8*)(apg + (size_t)k0 * 512))[1];
        const float* bp = bpg + (size_t)k0 * 512;
        *(float4*)&bv[0]  = ((const float4*)bp)[0];
        *(float4*)&bv[4]  = ((const float4*)bp)[1];
        *(float4*)&bv[8]  = ((const float4*)bp)[2];
        *(float4*)&bv[12] = ((const float4*)bp)[3];
    };
    auto STAGE = [&](int pp) {
#pragma unroll
        for (int j = 0; j < 8; ++j) {
            As[pp][swz(m0 + j, kk >> 3) + (kk & 7)]     = a0[j];
            As[pp][swz(m0 + 8 + j, kk >> 3) + (kk & 7)] = a1[j];
            Bs[pp][swz(m0 + j, kk >> 3) + (kk & 7)]     = (_Float16)bv[j];
            Bs[pp][swz(m0 + 8 + j, kk >> 3) + (kk & 7)] = (_Float16)bv[8 + j];
        }
    };

    LOAD(0);
    STAGE(0);

    int pp = 0;
    for (int k0 = 0; k0 < 512; k0 += 32) {
        __syncthreads();
        const bool more = (k0 + 32) < 512;
        if (more) LOAD(k0 + 32);

        h8 a[4], bb[4];
#pragma unroll
        for (int mi = 0; mi < 4; ++mi) a[mi] = *(const h8*)&As[pp][swz(wm * 64 + mi * 16 + c, q)];
#pragma unroll
        for (int ni = 0; ni < 4; ++ni) bb[ni] = *(const h8*)&Bs[pp][swz(wn * 64 + ni * 16 + c, q)];
#pragma unroll
        for (int mi = 0; mi < 4; ++mi)
#pragma unroll
            for (int ni = 0; ni < 4; ++ni)
                acc[mi][ni] = __builtin_amdgcn_mfma_f32_16x16x32_f16(a[mi], bb[ni], acc[mi][ni], 0, 0, 0);
        if (more) STAGE(pp ^ 1);
        pp ^= 1;
    }

#pragma unroll
    for (int mi = 0; mi < 4; ++mi)
#pragma unroll
        for (int ni = 0; ni < 4; ++ni) {
            int col = bn + wn * 64 + ni * 16 + c;
            int rowb = bm + wm * 64 + mi * 16 + q * 4;
#pragma unroll
            for (int r = 0; r < 4; ++r)
                outA[base + (size_t)(rowb + r) * 512 + col] = acc[mi][ni][r];
        }
}

extern "C" void kernel_launch(void* const* d_in, const int* in_sizes, int n_in,
                              void* d_out, int out_size, void* d_ws, size_t ws_size,
                              hipStream_t stream) {
    const float* P = (const float*)d_in[0];
    const float* H = (const float*)d_in[1];
    const float* W = (const float*)d_in[2];
    float* out = (float*)d_out;

    _Float16* ws16 = (_Float16*)d_ws;
    _Float16* F    = ws16;                       // F_p|F_h: 2*TOT (dead after score)
    _Float16* attn = ws16 + 2 * TOT_ELEMS;       // TOT
    _Float16* WTH  = attn;                       // WT in attn region (dead
    _Float16* WTL  = attn + BATCH_ELEMS;         //  before score writes attn)
    _Float16* X16  = (_Float16*)d_out;           // d_out f16 [0,2T): dead after proj
    _Float16* HT   = X16 + 2 * TOT_ELEMS;        // d_out f16 [2T,3T): dead after score

    conv16_kernel<<<dim3(8192, 1, 2), 256, 0, stream>>>(P, H, X16);
    transpose_f16_kernel<true><<<dim3(8, 8, 1), 256, 0, stream>>>(W, WTH, WTL);
    transpose_h16_kernel<<<dim3(8, 8, NB), 256, 0, stream>>>(X16 + TOT_ELEMS, HT);
    proj_tanh_kernel<<<dim3(256, 4, 2), 256, 0, stream>>>(X16, WTH, WTL, F);
    score_softmax_beta_kernel<<<dim3(8, NB), 256, 0, stream>>>(F, HT, attn, out);
    alphas_gemm_kernel<<<dim3(4, 4, NB), 256, 0, stream>>>(attn, P, out + TOT_ELEMS);
}

// Round 8
// 481.551 us; speedup vs baseline: 1.1126x; 1.0465x over previous
//
#include <hip/hip_runtime.h>
#include <hip/hip_fp16.h>

// Problem: B=64, L=512, D=512, A=512
//   F_p = tanh(P @ W), F_h = tanh(H @ W)        [f16; 2-term split MFMA Ah*(Bh+Bl)]
//   S = F_p @ F_h^T ; attn = softmax_rows(S)
//   betas  = attn   @ H  -> d_out[0 .. 16M)
//   alphas = attn^T @ P  -> d_out[16M .. 32M)
//
// R7 (resubmit; prior round was an infra failure, no result): XCD-locality fix.
// Block IDs round-robin the 8 XCDs, so BATCH goes in blockIdx.x everywhere a
// batch-shared operand exists: all blocks of batch b then share XCD b%8 and
// its L2 serves the shared operand (Fh in score; attn/HT/PT in out_gemm)
// instead of 8-16 HBM copies (R6 measured 301MB FETCH on score_beta from
// exactly this). Betas unfused (R6 fusion: occupancy 10%, net negative).
// proj keeps its accidental-but-correct XCD layout.
//
// ws (f16, 3*TOT): F_p|F_h [0,2T) -- dead after score -> reused for PT|HT;
//                  attn [2T,3T)  (WTH|WTL live there until proj done)
// d_out: X16 = f16(P|H) [0,2T) -- dead after transpose_hp16; outputs overwrite.

#define NB 64
#define NL 512
#define ND 512
#define BATCH_ELEMS (512 * 512)            // 262144
#define TOT_ELEMS   ((size_t)NB * NL * ND) // 16777216

typedef _Float16 h8 __attribute__((ext_vector_type(8)));
typedef float f4 __attribute__((ext_vector_type(4)));

// LDS tile layout: [row][32 k] f16, 16B chunks XOR-swizzled by ((row>>1)^(row>>4))&3.
__device__ __forceinline__ int swz(int row, int chunk) {
    return (row << 5) + ((chunk ^ (((row >> 1) ^ (row >> 4)) & 3)) << 3);
}

// async global->LDS 16B: wave-uniform LDS base, per-lane global src.
__device__ __forceinline__ void gld16(const _Float16* g, _Float16* l) {
    __builtin_amdgcn_global_load_lds(
        (const __attribute__((address_space(1))) void*)g,
        (__attribute__((address_space(3))) void*)l, 16, 0, 0);
}

__device__ __forceinline__ float fast_tanh(float x) {
    float e = __expf(2.0f * x);            // inf-safe: x>>0 -> 1, x<<0 -> -1
    return 1.0f - 2.0f / (e + 1.0f);
}

// ------------- Prep: X16 = f16(P|H), stored in d_out scratch -----------------
__global__ __launch_bounds__(256) void conv16_kernel(
    const float* __restrict__ P, const float* __restrict__ H,
    _Float16* __restrict__ X16)
{
    const int z = blockIdx.z;
    const float* src = z ? H : P;
    _Float16* dst = X16 + (size_t)z * TOT_ELEMS;
    size_t i = ((size_t)blockIdx.x * 256 + threadIdx.x) * 8;
    float4 v0 = ((const float4*)(src + i))[0];
    float4 v1 = ((const float4*)(src + i))[1];
    h8 o;
    o[0] = (_Float16)v0.x; o[1] = (_Float16)v0.y;
    o[2] = (_Float16)v0.z; o[3] = (_Float16)v0.w;
    o[4] = (_Float16)v1.x; o[5] = (_Float16)v1.y;
    o[6] = (_Float16)v1.z; o[7] = (_Float16)v1.w;
    *(h8*)(dst + i) = o;
}

// ------------- Prep: W -> WT hi/lo f16 (1 block-layer, f32 source) -----------
template <bool WITH_LO>
__global__ __launch_bounds__(256) void transpose_f16_kernel(
    const float* __restrict__ src, _Float16* __restrict__ dstH,
    _Float16* __restrict__ dstL)
{
    __shared__ float tile[64 * 68];
    const size_t base = (size_t)blockIdx.z * BATCH_ELEMS;
    const int r0 = blockIdx.y * 64, c0 = blockIdx.x * 64;
    const int t = threadIdx.x;
    {
        int r = t >> 2, cq = (t & 3) * 16;
        const float* sp = src + base + (size_t)(r0 + r) * 512 + c0 + cq;
        *(float4*)&tile[r * 68 + cq]      = ((const float4*)sp)[0];
        *(float4*)&tile[r * 68 + cq + 4]  = ((const float4*)sp)[1];
        *(float4*)&tile[r * 68 + cq + 8]  = ((const float4*)sp)[2];
        *(float4*)&tile[r * 68 + cq + 12] = ((const float4*)sp)[3];
    }
    __syncthreads();
    {
        int c = t >> 2, rq = (t & 3) * 16;
        _Float16 hv[16], lv[16];
#pragma unroll
        for (int j = 0; j < 16; ++j) {
            float v = tile[(rq + j) * 68 + c];
            hv[j] = (_Float16)v;
            if (WITH_LO) lv[j] = (_Float16)(v - (float)hv[j]);
        }
        _Float16* dp = dstH + base + (size_t)(c0 + c) * 512 + r0 + rq;
        *(h8*)dp = *(h8*)&hv[0];
        *(h8*)(dp + 8) = *(h8*)&hv[8];
        if (WITH_LO) {
            _Float16* dl = dstL + base + (size_t)(c0 + c) * 512 + r0 + rq;
            *(h8*)dl = *(h8*)&lv[0];
            *(h8*)(dl + 8) = *(h8*)&lv[8];
        }
    }
}

// ------------- Prep: PT|HT from X16 (f16 -> f16 transpose) -------------------
// z in [0,128): src = X16 + z*BATCH (P batches then H), dst = ws + z*BATCH
// (PT region [0,T) then HT region [T,2T) -- same linear map).
__global__ __launch_bounds__(256) void transpose_hp16_kernel(
    const _Float16* __restrict__ X16, _Float16* __restrict__ dstbase)
{
    __shared__ __align__(16) _Float16 tile[64 * 64];
    const size_t base = (size_t)blockIdx.z * BATCH_ELEMS;
    const int r0 = blockIdx.y * 64, c0 = blockIdx.x * 64;
    const int t = threadIdx.x;
    {
        int r = t >> 2, cq = (t & 3) * 16;
        const _Float16* sp = X16 + base + (size_t)(r0 + r) * 512 + c0 + cq;
        h8 v0 = ((const h8*)sp)[0];
        h8 v1 = ((const h8*)sp)[1];
        int f = ((r >> 1) ^ (r >> 4)) & 7;
        *(h8*)&tile[r * 64 + (((cq >> 3) ^ f) << 3)]       = v0;
        *(h8*)&tile[r * 64 + ((((cq >> 3) + 1) ^ f) << 3)] = v1;
    }
    __syncthreads();
    {
        int c = t >> 2, rq = (t & 3) * 16;
        _Float16 hv[16];
#pragma unroll
        for (int j = 0; j < 16; ++j) {
            int row = rq + j;
            int f = ((row >> 1) ^ (row >> 4)) & 7;
            hv[j] = tile[row * 64 + (((c >> 3) ^ f) << 3) + (c & 7)];
        }
        _Float16* dp = dstbase + base + (size_t)(c0 + c) * 512 + r0 + rq;
        *(h8*)dp = *(h8*)&hv[0];
        *(h8*)(dp + 8) = *(h8*)&hv[8];
    }
}

// ---------------- Kernel 1: F = tanh(X16 @ W), 2-term split f16 MFMA ---------
// R4 form (measured 109us): all staging via gld16, 1 barrier/k-step.
// Grid (256,4,2): same-A-row blocks differ by 256 in id -> same XCD already.
__global__ __launch_bounds__(256) void proj_tanh_kernel(
    const _Float16* __restrict__ X16,
    const _Float16* __restrict__ WTH, const _Float16* __restrict__ WTL,
    _Float16* __restrict__ Fout)
{
    __shared__ __align__(16) _Float16 AsH[2][128 * 32];
    __shared__ __align__(16) _Float16 BsH[2][128 * 32], BsL[2][128 * 32];

    const int z = blockIdx.z;
    const _Float16* X = X16 + (size_t)z * TOT_ELEMS;
    _Float16* F = Fout + (size_t)z * TOT_ELEMS;
    const int r0 = blockIdx.x * 128;
    const int n0 = blockIdx.y * 128;

    const int t = threadIdx.x;
    const int lane = t & 63, w4 = t >> 6;
    const int q = lane >> 4, c = lane & 15;
    const int wm = w4 >> 1, wn = w4 & 1;

    f4 acc[4][4] = {};

    const int lr = w4 * 16 + (lane >> 2);
    const int sb = ((lr >> 1) ^ (lr >> 4)) & 3;
    const int ch = ((lane & 3) ^ sb) * 8;
    const _Float16* sA0 = X + (size_t)(r0 + lr) * 512 + ch;
    const _Float16* sA1 = sA0 + (size_t)64 * 512;
    const _Float16* sH0 = WTH + (size_t)(n0 + lr) * 512 + ch;
    const _Float16* sH1 = sH0 + (size_t)64 * 512;
    const _Float16* sL0 = WTL + (size_t)(n0 + lr) * 512 + ch;
    const _Float16* sL1 = sL0 + (size_t)64 * 512;
    const int d0 = (w4 * 16) * 32, d1 = (64 + w4 * 16) * 32;

    auto STAGE = [&](int pp, int k0) {
        gld16(sA0 + k0, &AsH[pp][d0]);
        gld16(sA1 + k0, &AsH[pp][d1]);
        gld16(sH0 + k0, &BsH[pp][d0]);
        gld16(sH1 + k0, &BsH[pp][d1]);
        gld16(sL0 + k0, &BsL[pp][d0]);
        gld16(sL1 + k0, &BsL[pp][d1]);
    };

    STAGE(0, 0);
    __syncthreads();

    for (int ks = 0; ks < 16; ++ks) {
        const int pp = ks & 1;
        if (ks + 1 < 16) STAGE(pp ^ 1, (ks + 1) << 5);

        h8 aH[4], bH[4], bL[4];
#pragma unroll
        for (int mi = 0; mi < 4; ++mi)
            aH[mi] = *(const h8*)&AsH[pp][swz(wm * 64 + mi * 16 + c, q)];
#pragma unroll
        for (int ni = 0; ni < 4; ++ni) {
            bH[ni] = *(const h8*)&BsH[pp][swz(wn * 64 + ni * 16 + c, q)];
            bL[ni] = *(const h8*)&BsL[pp][swz(wn * 64 + ni * 16 + c, q)];
        }
#pragma unroll
        for (int mi = 0; mi < 4; ++mi)
#pragma unroll
            for (int ni = 0; ni < 4; ++ni) {
                acc[mi][ni] = __builtin_amdgcn_mfma_f32_16x16x32_f16(aH[mi], bH[ni], acc[mi][ni], 0, 0, 0);
                acc[mi][ni] = __builtin_amdgcn_mfma_f32_16x16x32_f16(aH[mi], bL[ni], acc[mi][ni], 0, 0, 0);
            }
        __syncthreads();
    }

#pragma unroll
    for (int mi = 0; mi < 4; ++mi)
#pragma unroll
        for (int ni = 0; ni < 4; ++ni) {
            int col = n0 + wn * 64 + ni * 16 + c;
            int rowb = r0 + wm * 64 + mi * 16 + q * 4;
#pragma unroll
            for (int r = 0; r < 4; ++r)
                F[(size_t)(rowb + r) * 512 + col] = (_Float16)fast_tanh(acc[mi][ni][r]);
        }
}

// ---------------- Kernel 2: S = F_p @ F_h^T, row softmax -> attn f16 ---------
// Grid (NB, 8): batch in x -> all 8 p-blocks of batch b on XCD b%8, Fh L2-shared.
__global__ __launch_bounds__(256) void score_softmax_kernel(
    const _Float16* __restrict__ Fbase, _Float16* __restrict__ attn)
{
    __shared__ __align__(16) _Float16 As[2][64 * 32];
    __shared__ __align__(16) _Float16 Bs[2][512 * 32];
    __shared__ float redM[4 * 64], redS[4 * 64];

    const _Float16* Fp = Fbase;
    const _Float16* Fh = Fbase + TOT_ELEMS;
    const int b = blockIdx.x;                 // batch fastest -> XCD-local
    const int p0 = blockIdx.y * 64;
    const size_t fb = (size_t)b * BATCH_ELEMS;

    const int t = threadIdx.x, lane = t & 63, w = t >> 6;
    const int q = lane >> 4, c = lane & 15;

    f4 acc[4][8] = {};

    const int lr = w * 16 + (lane >> 2);
    const int sb = ((lr >> 1) ^ (lr >> 4)) & 3;
    const int ch = ((lane & 3) ^ sb) * 8;
    const _Float16* sA  = Fp + fb + (size_t)(p0 + lr) * 512 + ch;
    const _Float16* sB0 = Fh + fb + (size_t)lr * 512 + ch;
    const int dA = (w * 16) * 32;

    auto STAGE = [&](int pp, int k0) {
        gld16(sA + k0, &As[pp][dA]);
#pragma unroll
        for (int i = 0; i < 8; ++i)
            gld16(sB0 + (size_t)i * 64 * 512 + k0, &Bs[pp][(i * 64 + w * 16) * 32]);
    };

    STAGE(0, 0);
    __syncthreads();

    for (int ks = 0; ks < 16; ++ks) {
        const int pp = ks & 1;
        if (ks + 1 < 16) STAGE(pp ^ 1, (ks + 1) << 5);

        h8 a[4], bb[8];
#pragma unroll
        for (int mt = 0; mt < 4; ++mt) a[mt] = *(const h8*)&As[pp][swz(mt * 16 + c, q)];
#pragma unroll
        for (int nt = 0; nt < 8; ++nt) bb[nt] = *(const h8*)&Bs[pp][swz(w * 128 + nt * 16 + c, q)];
#pragma unroll
        for (int mt = 0; mt < 4; ++mt)
#pragma unroll
            for (int nt = 0; nt < 8; ++nt)
                acc[mt][nt] = __builtin_amdgcn_mfma_f32_16x16x32_f16(a[mt], bb[nt], acc[mt][nt], 0, 0, 0);
        __syncthreads();
    }

    // ---- softmax over the 512 cols; rows owned: mt*16 + q*4 + r ----
    float rmax[4][4];
#pragma unroll
    for (int mt = 0; mt < 4; ++mt)
#pragma unroll
        for (int r = 0; r < 4; ++r) {
            float m = acc[mt][0][r];
#pragma unroll
            for (int nt = 1; nt < 8; ++nt) m = fmaxf(m, acc[mt][nt][r]);
            rmax[mt][r] = m;
        }
#pragma unroll
    for (int s = 1; s < 16; s <<= 1)
#pragma unroll
        for (int mt = 0; mt < 4; ++mt)
#pragma unroll
            for (int r = 0; r < 4; ++r)
                rmax[mt][r] = fmaxf(rmax[mt][r], __shfl_xor(rmax[mt][r], s, 64));
    if (c == 0)
#pragma unroll
        for (int mt = 0; mt < 4; ++mt)
#pragma unroll
            for (int r = 0; r < 4; ++r)
                redM[w * 64 + mt * 16 + q * 4 + r] = rmax[mt][r];
    __syncthreads();

    float gmax[4][4];
#pragma unroll
    for (int mt = 0; mt < 4; ++mt)
#pragma unroll
        for (int r = 0; r < 4; ++r) {
            int row = mt * 16 + q * 4 + r;
            float m = redM[row];
#pragma unroll
            for (int w4i = 1; w4i < 4; ++w4i) m = fmaxf(m, redM[w4i * 64 + row]);
            gmax[mt][r] = m;
        }

    float rsum[4][4] = {};
#pragma unroll
    for (int mt = 0; mt < 4; ++mt)
#pragma unroll
        for (int nt = 0; nt < 8; ++nt)
#pragma unroll
            for (int r = 0; r < 4; ++r) {
                float e = __expf(acc[mt][nt][r] - gmax[mt][r]);
                acc[mt][nt][r] = e;
                rsum[mt][r] += e;
            }
#pragma unroll
    for (int s = 1; s < 16; s <<= 1)
#pragma unroll
        for (int mt = 0; mt < 4; ++mt)
#pragma unroll
            for (int r = 0; r < 4; ++r)
                rsum[mt][r] += __shfl_xor(rsum[mt][r], s, 64);
    if (c == 0)
#pragma unroll
        for (int mt = 0; mt < 4; ++mt)
#pragma unroll
            for (int r = 0; r < 4; ++r)
                redS[w * 64 + mt * 16 + q * 4 + r] = rsum[mt][r];
    __syncthreads();

    float inv[4][4];
#pragma unroll
    for (int mt = 0; mt < 4; ++mt)
#pragma unroll
        for (int r = 0; r < 4; ++r) {
            int row = mt * 16 + q * 4 + r;
            float s = redS[row] + redS[64 + row] + redS[128 + row] + redS[192 + row];
            inv[mt][r] = 1.0f / s;
        }

#pragma unroll
    for (int mt = 0; mt < 4; ++mt)
#pragma unroll
        for (int nt = 0; nt < 8; ++nt) {
            int col = w * 128 + nt * 16 + c;
#pragma unroll
            for (int r = 0; r < 4; ++r) {
                int row = p0 + mt * 16 + q * 4 + r;
                attn[fb + (size_t)row * 512 + col] = (_Float16)(acc[mt][nt][r] * inv[mt][r]);
            }
        }
}

// ------- Kernels 3+4 merged: C = A(^T) @ B; zz<64: betas (attn@H via HT),
//         zz>=64: alphas (attn^T@P via PT). zz in blockIdx.x -> batch b on
//         XCD b%8 for BOTH halves; attn/HT/PT L2-shared (and attn L2-hot
//         from score, which used the same b->XCD mapping). ------------------
__global__ __launch_bounds__(256) void out_gemm_kernel(
    const _Float16* __restrict__ Amat, const _Float16* __restrict__ HT,
    const _Float16* __restrict__ PT, float* __restrict__ out)
{
    __shared__ __align__(16) _Float16 As[2][128 * 32];
    __shared__ __align__(16) _Float16 Bs[2][128 * 32];

    const int zz = blockIdx.x;               // batch+half fastest -> XCD-local
    const bool transA = zz >= NB;
    const int b = transA ? zz - NB : zz;
    const _Float16* BT = transA ? PT : HT;
    float* Cout = transA ? out + TOT_ELEMS : out;

    const int bn = blockIdx.y * 128, bm = blockIdx.z * 128;
    const size_t base = (size_t)b * BATCH_ELEMS;

    const int t = threadIdx.x, lane = t & 63, w4 = t >> 6;
    const int q = lane >> 4, c = lane & 15;
    const int wm = w4 >> 1, wn = w4 & 1;

    f4 acc[4][4] = {};

    // A gld16 addressing (direct path)
    const int lr = w4 * 16 + (lane >> 2);
    const int sb = ((lr >> 1) ^ (lr >> 4)) & 3;
    const int ch = ((lane & 3) ^ sb) * 8;
    const _Float16* sA0 = Amat + base + (size_t)(bm + lr) * 512 + ch;
    const _Float16* sA1 = sA0 + (size_t)64 * 512;
    const _Float16* sB0 = BT + base + (size_t)(bn + lr) * 512 + ch;
    const _Float16* sB1 = sB0 + (size_t)64 * 512;
    const int d0 = (w4 * 16) * 32, d1 = (64 + w4 * 16) * 32;

    // transA reg-staged scatter addressing
    const int kk = t >> 3, m0 = (t & 7) * 16;
    const _Float16* apg_t = Amat + base + (size_t)kk * 512 + bm + m0;
    h8 a0, a1;

    auto STAGE_B = [&](int pp, int k0) {
        gld16(sB0 + k0, &Bs[pp][d0]);
        gld16(sB1 + k0, &Bs[pp][d1]);
    };
    auto STAGE_A_DIRECT = [&](int pp, int k0) {
        gld16(sA0 + k0, &As[pp][d0]);
        gld16(sA1 + k0, &As[pp][d1]);
    };
    auto LOAD_A_T = [&](int k0) {
        a0 = ((const h8*)(apg_t + (size_t)k0 * 512))[0];
        a1 = ((const h8*)(apg_t + (size_t)k0 * 512))[1];
    };
    auto STAGE_A_T = [&](int pp) {
#pragma unroll
        for (int j = 0; j < 8; ++j) {
            As[pp][swz(m0 + j, kk >> 3) + (kk & 7)]     = a0[j];
            As[pp][swz(m0 + 8 + j, kk >> 3) + (kk & 7)] = a1[j];
        }
    };

    STAGE_B(0, 0);
    if (!transA) {
        STAGE_A_DIRECT(0, 0);
    } else {
        LOAD_A_T(0);
        STAGE_A_T(0);
    }
    __syncthreads();

    for (int ks = 0; ks < 16; ++ks) {
        const int pp = ks & 1;
        const bool more = (ks + 1) < 16;
        const int k0n = (ks + 1) << 5;
        if (more) {
            STAGE_B(pp ^ 1, k0n);
            if (!transA) STAGE_A_DIRECT(pp ^ 1, k0n);
            else LOAD_A_T(k0n);
        }

        h8 a[4], bb[4];
#pragma unroll
        for (int mi = 0; mi < 4; ++mi) a[mi] = *(const h8*)&As[pp][swz(wm * 64 + mi * 16 + c, q)];
#pragma unroll
        for (int ni = 0; ni < 4; ++ni) bb[ni] = *(const h8*)&Bs[pp][swz(wn * 64 + ni * 16 + c, q)];
#pragma unroll
        for (int mi = 0; mi < 4; ++mi)
#pragma unroll
            for (int ni = 0; ni < 4; ++ni)
                acc[mi][ni] = __builtin_amdgcn_mfma_f32_16x16x32_f16(a[mi], bb[ni], acc[mi][ni], 0, 0, 0);
        if (more && transA) STAGE_A_T(pp ^ 1);
        __syncthreads();
    }

#pragma unroll
    for (int mi = 0; mi < 4; ++mi)
#pragma unroll
        for (int ni = 0; ni < 4; ++ni) {
            int col = bn + wn * 64 + ni * 16 + c;
            int rowb = bm + wm * 64 + mi * 16 + q * 4;
#pragma unroll
            for (int r = 0; r < 4; ++r)
                Cout[base + (size_t)(rowb + r) * 512 + col] = acc[mi][ni][r];
        }
}

extern "C" void kernel_launch(void* const* d_in, const int* in_sizes, int n_in,
                              void* d_out, int out_size, void* d_ws, size_t ws_size,
                              hipStream_t stream) {
    const float* P = (const float*)d_in[0];
    const float* H = (const float*)d_in[1];
    const float* W = (const float*)d_in[2];
    float* out = (float*)d_out;

    _Float16* ws16 = (_Float16*)d_ws;
    _Float16* F    = ws16;                       // F_p|F_h: 2*TOT (dead after score)
    _Float16* PT   = ws16;                       // PT|HT reuse F region after score
    _Float16* HT   = ws16 + TOT_ELEMS;
    _Float16* attn = ws16 + 2 * TOT_ELEMS;       // TOT
    _Float16* WTH  = attn;                       // WT in attn region (dead
    _Float16* WTL  = attn + BATCH_ELEMS;         //  before score writes attn)
    _Float16* X16  = (_Float16*)d_out;           // d_out scratch [0,2T) f16

    conv16_kernel<<<dim3(8192, 1, 2), 256, 0, stream>>>(P, H, X16);
    transpose_f16_kernel<true><<<dim3(8, 8, 1), 256, 0, stream>>>(W, WTH, WTL);
    proj_tanh_kernel<<<dim3(256, 4, 2), 256, 0, stream>>>(X16, WTH, WTL, F);
    score_softmax_kernel<<<dim3(NB, 8), 256, 0, stream>>>(F, attn);
    transpose_hp16_kernel<<<dim3(8, 8, 2 * NB), 256, 0, stream>>>(X16, ws16);
    out_gemm_kernel<<<dim3(2 * NB, 4, 4), 256, 0, stream>>>(attn, HT, PT, out);
}